// Round 1
// baseline (953.842 us; speedup 1.0000x reference)
//
#include <hip/hip_runtime.h>
#include <math.h>

#define NA 8000
#define NV 4000
#define NN 12000
#define FEAT 32
#define HD 64
#define NLAYER 12
#define E_AA 80000
#define E_AV 120000
#define E_VV 60000
#define E_TOT 260000
#define ENC_SIZE (NV * HD)

// ---------------------------------------------------------------------------
// kNN: one wave (64 lanes) per query. Each lane keeps a sorted top-K of its
// strided slice of candidates in registers, then K rounds of lexicographic
// (d2, idx) butterfly-min merge reproduce jax.lax.top_k's stable ordering.
// d2 uses the reference's algebraic form (qq - 2*dot) + cc.
// ---------------------------------------------------------------------------
template<int K>
__global__ __launch_bounds__(64) void knn_kernel(
    const float* __restrict__ qpos,
    const float* __restrict__ cpos, int Nc,
    int c_off, int* __restrict__ out_src)
{
  const int q    = blockIdx.x;
  const int lane = threadIdx.x;
  const float qx = qpos[q*3+0], qy = qpos[q*3+1], qz = qpos[q*3+2];
  const float qq = (qx*qx + qy*qy) + qz*qz;

  float bd[K]; int bi[K];
#pragma unroll
  for (int i = 0; i < K; ++i) { bd[i] = INFINITY; bi[i] = 0x7fffffff; }

  for (int c = lane; c < Nc; c += 64) {
    const float cx = cpos[c*3+0], cy = cpos[c*3+1], cz = cpos[c*3+2];
    const float cc  = (cx*cx + cy*cy) + cz*cz;
    const float dot = qx*cx + qy*cy + qz*cz;
    const float d2  = (qq - 2.0f*dot) + cc;
    if (d2 >= bd[K-1]) continue;           // equal d2 loses to earlier index
    float vd = d2; int vi = c;
#pragma unroll
    for (int i = 0; i < K; ++i) {          // bubble-insert, all static indices
      const bool lt = (vd < bd[i]) || (vd == bd[i] && vi < bi[i]);
      const float td = lt ? bd[i] : vd; const int ti = lt ? bi[i] : vi;
      if (lt) { bd[i] = vd; bi[i] = vi; }
      vd = td; vi = ti;
    }
  }

  for (int r = 0; r < K; ++r) {
    const float hd0 = bd[0]; const int hi0 = bi[0];
    float md = hd0; int mi = hi0;
#pragma unroll
    for (int off = 1; off < 64; off <<= 1) {
      const float od = __shfl_xor(md, off);
      const int   oi = __shfl_xor(mi, off);
      if (od < md || (od == md && oi < mi)) { md = od; mi = oi; }
    }
    if (lane == 0) out_src[q*K + r] = mi + c_off;
    if (md == hd0 && mi == hi0) {          // unique owner pops its head
#pragma unroll
      for (int i = 0; i < K-1; ++i) { bd[i] = bd[i+1]; bi[i] = bi[i+1]; }
      bd[K-1] = INFINITY; bi[K-1] = 0x7fffffff;
    }
  }
}

// ---------------------------------------------------------------------------
// Input projection: x = [atom_x@Wa + ba ; vox_x@Wv + bv].  4 nodes / block,
// one wave per node, lane t = output column. Also writes snapshot slot 0
// (initial vox rows) for the final concat head.
// ---------------------------------------------------------------------------
__global__ __launch_bounds__(256) void proj_kernel(
    const float* __restrict__ atom_x, const float* __restrict__ vox_x,
    const float* __restrict__ Wa, const float* __restrict__ ba,
    const float* __restrict__ Wv, const float* __restrict__ bv,
    float* __restrict__ x, float* __restrict__ snap0)
{
  const int node = blockIdx.x * 4 + (threadIdx.x >> 6);
  const int t    = threadIdx.x & 63;
  const float* in; const float* W; const float* b;
  if (node < NA) { in = atom_x + node*FEAT;       W = Wa; b = ba; }
  else           { in = vox_x + (node-NA)*FEAT;   W = Wv; b = bv; }
  float acc = b[t];
#pragma unroll
  for (int j = 0; j < FEAT; ++j) acc += in[j] * W[j*HD + t];
  x[node*HD + t] = acc;
  if (node >= NA) snap0[(node-NA)*HD + t] = acc;
}

// ---------------------------------------------------------------------------
// Edge attribute MLP: dist -> relu(dist*w1+b1) @ w2 + b2  (scalar->8->1)
// dist computed diff-based (matches jnp.linalg.norm(pos[s]-pos[d])).
// ---------------------------------------------------------------------------
__device__ __forceinline__ void load_pos(const float* ap, const float* vp,
                                         int i, float& px, float& py, float& pz)
{
  const float* p = (i < NA) ? (ap + i*3) : (vp + (i - NA)*3);
  px = p[0]; py = p[1]; pz = p[2];
}

__global__ __launch_bounds__(256) void edge_attr_kernel(
    const float* __restrict__ atom_pos, const float* __restrict__ vox_pos,
    const int* __restrict__ srcA, const int* __restrict__ srcAV,
    const int* __restrict__ srcVV,
    const float* __restrict__ w1, const float* __restrict__ b1,
    const float* __restrict__ w2, const float* __restrict__ b2,
    float* __restrict__ eattr)
{
  const int e = blockIdx.x * 256 + threadIdx.x;
  if (e >= E_TOT) return;
  int s, d, mi;
  if (e < E_AA)              { mi = 0; s = srcA[e];                 d = e / 10; }
  else if (e < E_AA + E_AV)  { mi = 1; const int t = e - E_AA;      s = srcAV[t]; d = t / 15; }
  else                       { mi = 2; const int t = e - E_AA - E_AV; s = srcVV[t]; d = NA + t / 15; }
  float sx, sy, sz, dx_, dy_, dz_;
  load_pos(atom_pos, vox_pos, s, sx, sy, sz);
  load_pos(atom_pos, vox_pos, d, dx_, dy_, dz_);
  const float ex = sx - dx_, ey = sy - dy_, ez = sz - dz_;
  const float dist = sqrtf(ex*ex + ey*ey + ez*ez);
  float acc = b2[mi];
#pragma unroll
  for (int j = 0; j < 8; ++j) {
    float h = dist * w1[mi*8 + j] + b1[mi*8 + j];
    h = (h > 0.0f) ? h : 0.0f;
    acc += h * w2[mi*8 + j];
  }
  eattr[e] = acc;
}

// ---------------------------------------------------------------------------
// Layer part A: LayerNorm (two-pass) + s = h@Ws[l], d = h@Wd[l].
// 4 nodes / block, one wave per node, lane t = output column.
// ---------------------------------------------------------------------------
__global__ __launch_bounds__(256) void ln_qk_kernel(
    const float* __restrict__ x,
    const float* __restrict__ ln_g, const float* __restrict__ ln_b,
    const float* __restrict__ Ws, const float* __restrict__ Wd,
    float* __restrict__ sbuf, float* __restrict__ dbuf, int l)
{
  const int wid  = threadIdx.x >> 6;
  const int node = blockIdx.x * 4 + wid;
  const int t    = threadIdx.x & 63;
  __shared__ float hsh[4][HD];

  const float v = x[node*HD + t];
  float m = v;
#pragma unroll
  for (int off = 1; off < 64; off <<= 1) m += __shfl_xor(m, off);
  m *= (1.0f/64.0f);
  const float c = v - m;
  float var = c * c;
#pragma unroll
  for (int off = 1; off < 64; off <<= 1) var += __shfl_xor(var, off);
  var *= (1.0f/64.0f);
  const float hn = c * rsqrtf(var + 1e-5f) * ln_g[l*HD + t] + ln_b[l*HD + t];
  hsh[wid][t] = hn;
  __syncthreads();

  const float* ws = Ws + l*HD*HD;
  const float* wd = Wd + l*HD*HD;
  float accs = 0.0f, accd = 0.0f;
#pragma unroll
  for (int j = 0; j < HD; ++j) {
    const float hj = hsh[wid][j];
    accs += hj * ws[j*HD + t];
    accd += hj * wd[j*HD + t];
  }
  sbuf[node*HD + t] = accs;
  dbuf[node*HD + t] = accd;
}

// ---------------------------------------------------------------------------
// Layer part B: per-destination-node attention aggregation + residual ReLU.
// One wave per node; lane t = feature (head = t/16). dst edges are contiguous
// by construction so no atomics / segment ops are needed (deterministic).
// ---------------------------------------------------------------------------
template<int NE, bool IS_ATOM>
__global__ __launch_bounds__(64) void gat_agg_kernel(
    float* __restrict__ x,
    const float* __restrict__ sbuf, const float* __restrict__ dbuf,
    const float* __restrict__ eattr,
    const int* __restrict__ srcA, const int* __restrict__ srcAV,
    const int* __restrict__ srcVV,
    const float* __restrict__ We, const float* __restrict__ att, int l,
    float* __restrict__ snap)
{
  const int lane = threadIdx.x;
  const int n    = IS_ATOM ? blockIdx.x : (NA + blockIdx.x);
  const float wet  = We[l*HD + lane];
  const float attv = att[l*HD + lane];
  const float dn   = dbuf[n*HD + lane];

  int esrc[NE]; float escore[NE];
#pragma unroll
  for (int e = 0; e < NE; ++e) {
    int src, eidx;
    if (IS_ATOM) {
      if (e < 10) { src = srcA[n*10 + e];       eidx = n*10 + e; }
      else        { src = srcAV[n*15 + (e-10)]; eidx = E_AA + n*15 + (e-10); }
    } else {
      const int nv = blockIdx.x;
      src = srcVV[nv*15 + e]; eidx = E_AA + E_AV + nv*15 + e;
    }
    esrc[e] = src;
    float m = sbuf[src*HD + lane] + dn + eattr[eidx] * wet;
    m = (m >= 0.0f) ? m : 0.2f * m;        // leaky_relu(0.2)
    float v = m * attv;                     // einsum over d within head
    v += __shfl_xor(v, 1); v += __shfl_xor(v, 2);
    v += __shfl_xor(v, 4); v += __shfl_xor(v, 8);
    escore[e] = v;                          // per-head score (16-lane groups)
  }

  float mx = -INFINITY;
#pragma unroll
  for (int e = 0; e < NE; ++e) mx = fmaxf(mx, escore[e]);
  float den = 0.0f;
#pragma unroll
  for (int e = 0; e < NE; ++e) {
    const float a = expf(escore[e] - mx);
    escore[e] = a; den += a;
  }
  const float inv = 1.0f / den;
  float msg = 0.0f;
#pragma unroll
  for (int e = 0; e < NE; ++e)
    msg += (escore[e] * inv) * sbuf[esrc[e]*HD + lane];

  float xv = x[n*HD + lane] + msg;
  xv = (xv > 0.0f) ? xv : 0.0f;
  x[n*HD + lane] = xv;
  if (!IS_ATOM && snap != nullptr) snap[blockIdx.x*HD + lane] = xv;
}

// ---------------------------------------------------------------------------
// Output head: cat[448] @ Wo1 -> relu -> @ Wo2, per vox node (one wave each).
// ---------------------------------------------------------------------------
__global__ __launch_bounds__(64) void head_kernel(
    const float* __restrict__ snaps,   // [7][NV][HD]
    const float* __restrict__ Wo1, const float* __restrict__ bo1,
    const float* __restrict__ Wo2, const float* __restrict__ bo2,
    float* __restrict__ out)
{
  const int n = blockIdx.x;
  const int t = threadIdx.x;
  __shared__ float cat[7*HD];
  __shared__ float o1[HD];
#pragma unroll
  for (int c = 0; c < 7; ++c)
    cat[c*HD + t] = snaps[(size_t)c*NV*HD + n*HD + t];
  __syncthreads();
  float acc = bo1[t];
  for (int j = 0; j < 7*HD; ++j) acc += cat[j] * Wo1[j*HD + t];
  acc = fmaxf(acc, 0.0f);
  o1[t] = acc;
  __syncthreads();
  float acc2 = bo2[t];
#pragma unroll
  for (int j = 0; j < HD; ++j) acc2 += o1[j] * Wo2[j*HD + t];
  out[n*HD + t] = acc2;
}

__global__ __launch_bounds__(256) void copy_pos_kernel(
    const float* __restrict__ vp, float* __restrict__ out)
{
  const int i = blockIdx.x * 256 + threadIdx.x;
  if (i < NV*3) out[ENC_SIZE + i] = vp[i];
}

// ---------------------------------------------------------------------------
extern "C" void kernel_launch(void* const* d_in, const int* in_sizes, int n_in,
                              void* d_out, int out_size, void* d_ws, size_t ws_size,
                              hipStream_t stream)
{
  const float* atom_x    = (const float*)d_in[0];
  const float* atom_pos  = (const float*)d_in[1];
  const float* vox_x     = (const float*)d_in[2];
  const float* vox_pos   = (const float*)d_in[3];
  const float* W_atom_in = (const float*)d_in[4];
  const float* b_atom_in = (const float*)d_in[5];
  const float* W_vox_in  = (const float*)d_in[6];
  const float* b_vox_in  = (const float*)d_in[7];
  const float* emlp_w1   = (const float*)d_in[8];
  const float* emlp_b1   = (const float*)d_in[9];
  const float* emlp_w2   = (const float*)d_in[10];
  const float* emlp_b2   = (const float*)d_in[11];
  const float* ln_g      = (const float*)d_in[12];
  const float* ln_b      = (const float*)d_in[13];
  const float* Ws        = (const float*)d_in[14];
  const float* Wd        = (const float*)d_in[15];
  const float* We        = (const float*)d_in[16];
  const float* att       = (const float*)d_in[17];
  const float* Wo1       = (const float*)d_in[18];
  const float* bo1       = (const float*)d_in[19];
  const float* Wo2       = (const float*)d_in[20];
  const float* bo2       = (const float*)d_in[21];
  float* out = (float*)d_out;

  // workspace layout (floats), ~18.5 MB total
  float* ws    = (float*)d_ws;
  float* x     = ws;                       // [NN][HD]
  float* sbuf  = x     + (size_t)NN*HD;    // [NN][HD]
  float* dbuf  = sbuf  + (size_t)NN*HD;    // [NN][HD]
  float* eattr = dbuf  + (size_t)NN*HD;    // [E_TOT]
  float* snaps = eattr + E_TOT;            // [7][NV][HD]
  int*   srcA  = (int*)(snaps + (size_t)7*NV*HD);  // [E_AA]
  int*   srcAV = srcA  + E_AA;             // [E_AV]
  int*   srcVV = srcAV + E_AV;             // [E_VV]

  // 1. input projections (+ snapshot 0 = initial vox rows)
  proj_kernel<<<NN/4, 256, 0, stream>>>(atom_x, vox_x, W_atom_in, b_atom_in,
                                        W_vox_in, b_vox_in, x, snaps);
  // 2. kNN graphs
  knn_kernel<10><<<NA, 64, 0, stream>>>(atom_pos, atom_pos, NA, 0,  srcA);
  knn_kernel<15><<<NA, 64, 0, stream>>>(atom_pos, vox_pos,  NV, NA, srcAV);
  knn_kernel<15><<<NV, 64, 0, stream>>>(vox_pos,  vox_pos,  NV, NA, srcVV);
  // 3. edge attributes
  edge_attr_kernel<<<(E_TOT + 255)/256, 256, 0, stream>>>(
      atom_pos, vox_pos, srcA, srcAV, srcVV,
      emlp_w1, emlp_b1, emlp_w2, emlp_b2, eattr);
  // 4. 12 GAT layers
  for (int l = 0; l < NLAYER; ++l) {
    ln_qk_kernel<<<NN/4, 256, 0, stream>>>(x, ln_g, ln_b, Ws, Wd, sbuf, dbuf, l);
    gat_agg_kernel<25, true><<<NA, 64, 0, stream>>>(
        x, sbuf, dbuf, eattr, srcA, srcAV, srcVV, We, att, l, nullptr);
    float* snap = (l & 1) ? (snaps + (size_t)(l/2 + 1)*NV*HD) : nullptr;
    gat_agg_kernel<15, false><<<NV, 64, 0, stream>>>(
        x, sbuf, dbuf, eattr, srcA, srcAV, srcVV, We, att, l, snap);
  }
  // 5. output head + vox_pos passthrough
  head_kernel<<<NV, 64, 0, stream>>>(snaps, Wo1, bo1, Wo2, bo2, out);
  copy_pos_kernel<<<(NV*3 + 255)/256, 256, 0, stream>>>(vox_pos, out);
}

// Round 2
// 587.892 us; speedup vs baseline: 1.6225x; 1.6225x over previous
//
#include <hip/hip_runtime.h>
#include <math.h>

#define NA 8000
#define NV 4000
#define NN 12000
#define FEAT 32
#define HD 64
#define NLAYER 12
#define E_AA 80000
#define E_AV 120000
#define E_VV 60000
#define E_TOT 260000
#define ENC_SIZE (NV * HD)
#define EPS 1e-5f

__device__ __forceinline__ float wave_sum64(float v) {
#pragma unroll
  for (int off = 1; off < 64; off <<= 1) v += __shfl_xor(v, off);
  return v;
}

// ---------------------------------------------------------------------------
// kNN: 4 queries/block (one wave each), candidates tiled through LDS (SoA).
// Wave-global top-K: sorted (d2,idx) list distributed one entry per lane
// (lanes 0..K-1 meaningful). Qualification vs the true K-th best threshold ->
// insert events are rare; inserts are a 1-step shfl shift behind a SCALAR
// ballot branch (no exec divergence). Lexicographic tie-break == jax top_k.
// ---------------------------------------------------------------------------
template<int K>
__global__ __launch_bounds__(256) void knn_kernel(
    const float* __restrict__ qpos, const float* __restrict__ cpos,
    int Nc, int c_off, int* __restrict__ out_src)
{
  __shared__ float sx[256], sy[256], sz[256];
  const int tid  = threadIdx.x;
  const int wid  = tid >> 6, lane = tid & 63;
  const int q    = blockIdx.x * 4 + wid;
  const float qx = qpos[q*3+0], qy = qpos[q*3+1], qz = qpos[q*3+2];
  const float qq = (qx*qx + qy*qy) + qz*qz;

  float eD = INFINITY; int eI = 0x7fffffff;   // this lane's entry of the list
  float thrD = INFINITY;                       // broadcast K-th best

  for (int t0 = 0; t0 < Nc; t0 += 256) {
    __syncthreads();
    const int ci = t0 + tid;
    if (ci < Nc) {
      sx[tid] = cpos[ci*3+0];
      sy[tid] = cpos[ci*3+1];
      sz[tid] = cpos[ci*3+2];
    }
    __syncthreads();
    const int lim = Nc - t0;                   // candidates valid in tile
#pragma unroll
    for (int sub = 0; sub < 256; sub += 64) {
      const int j  = sub + lane;
      const float cx = sx[j], cy = sy[j], cz = sz[j];
      const float cc  = (cx*cx + cy*cy) + cz*cz;
      const float dot = qx*cx + qy*cy + qz*cz;
      const float d2  = (qq - 2.0f*dot) + cc;
      const bool qual = (j < lim) && (d2 < thrD);   // ties lose (idx larger)
      unsigned long long m = __ballot(qual);
      while (m) {                                   // wave-uniform loop
        const int sl = __ffsll(m) - 1;
        m &= (m - 1ULL);
        const float v  = __shfl(d2, sl);
        const int   vi = t0 + sub + sl;
        const bool stay = (eD < v) || (eD == v && eI < vi);
        const float pD = __shfl_up(eD, 1);
        const int   pI = __shfl_up(eI, 1);
        int pS = __shfl_up(stay ? 1 : 0, 1);
        if (lane == 0) pS = 1;
        eD = stay ? eD : (pS ? v  : pD);
        eI = stay ? eI : (pS ? vi : pI);
      }
      thrD = __shfl(eD, K-1);
    }
  }
  if (lane < K) out_src[q*K + lane] = eI + c_off;
}

// ---------------------------------------------------------------------------
// LayerNorm + s/d projection for one node row held across the wave's lanes.
// Bitwise-identical arithmetic to the previously-passing ln_qk kernel.
// ---------------------------------------------------------------------------
__device__ __forceinline__ void ln_sd(
    float v, int node, int lane, int l,
    const float* __restrict__ ln_g, const float* __restrict__ ln_b,
    const float* __restrict__ Ws, const float* __restrict__ Wd,
    float* __restrict__ sbuf, float* __restrict__ dbuf)
{
  const float m = wave_sum64(v) * (1.0f/64.0f);
  const float c = v - m;
  const float var = wave_sum64(c*c) * (1.0f/64.0f);
  const float hn = c * rsqrtf(var + EPS) * ln_g[l*HD + lane] + ln_b[l*HD + lane];
  const float* ws = Ws + l*HD*HD;
  const float* wd = Wd + l*HD*HD;
  float accs = 0.0f, accd = 0.0f;
#pragma unroll
  for (int j = 0; j < HD; ++j) {
    const float hj = __shfl(hn, j);
    accs += hj * ws[j*HD + lane];
    accd += hj * wd[j*HD + lane];
  }
  sbuf[node*HD + lane] = accs;
  dbuf[node*HD + lane] = accd;
}

// ---------------------------------------------------------------------------
// Fused first kernel: input projection + snapshot0 + LN(0) + s/d projection.
// One wave per node.
// ---------------------------------------------------------------------------
__global__ __launch_bounds__(64) void init_kernel(
    const float* __restrict__ atom_x, const float* __restrict__ vox_x,
    const float* __restrict__ Wa, const float* __restrict__ ba,
    const float* __restrict__ Wv, const float* __restrict__ bv,
    const float* __restrict__ ln_g, const float* __restrict__ ln_b,
    const float* __restrict__ Ws, const float* __restrict__ Wd,
    float* __restrict__ x, float* __restrict__ snap0,
    float* __restrict__ sbuf, float* __restrict__ dbuf)
{
  const int node = blockIdx.x;
  const int t    = threadIdx.x;
  const float* in; const float* W; const float* b;
  if (node < NA) { in = atom_x + node*FEAT;     W = Wa; b = ba; }
  else           { in = vox_x + (node-NA)*FEAT; W = Wv; b = bv; }
  float acc = b[t];
#pragma unroll
  for (int j = 0; j < FEAT; ++j) acc += in[j] * W[j*HD + t];
  x[node*HD + t] = acc;
  if (node >= NA) snap0[(node-NA)*HD + t] = acc;
  ln_sd(acc, node, t, 0, ln_g, ln_b, Ws, Wd, sbuf, dbuf);
}

// ---------------------------------------------------------------------------
// Edge attribute MLP (unchanged from passing version).
// ---------------------------------------------------------------------------
__device__ __forceinline__ void load_pos(const float* ap, const float* vp,
                                         int i, float& px, float& py, float& pz)
{
  const float* p = (i < NA) ? (ap + i*3) : (vp + (i - NA)*3);
  px = p[0]; py = p[1]; pz = p[2];
}

__global__ __launch_bounds__(256) void edge_attr_kernel(
    const float* __restrict__ atom_pos, const float* __restrict__ vox_pos,
    const int* __restrict__ srcA, const int* __restrict__ srcAV,
    const int* __restrict__ srcVV,
    const float* __restrict__ w1, const float* __restrict__ b1,
    const float* __restrict__ w2, const float* __restrict__ b2,
    float* __restrict__ eattr)
{
  const int e = blockIdx.x * 256 + threadIdx.x;
  if (e >= E_TOT) return;
  int s, d, mi;
  if (e < E_AA)              { mi = 0; s = srcA[e];                 d = e / 10; }
  else if (e < E_AA + E_AV)  { mi = 1; const int t = e - E_AA;      s = srcAV[t]; d = t / 15; }
  else                       { mi = 2; const int t = e - E_AA - E_AV; s = srcVV[t]; d = NA + t / 15; }
  float sx, sy, sz, dx_, dy_, dz_;
  load_pos(atom_pos, vox_pos, s, sx, sy, sz);
  load_pos(atom_pos, vox_pos, d, dx_, dy_, dz_);
  const float ex = sx - dx_, ey = sy - dy_, ez = sz - dz_;
  const float dist = sqrtf(ex*ex + ey*ey + ez*ez);
  float acc = b2[mi];
#pragma unroll
  for (int j = 0; j < 8; ++j) {
    float h = dist * w1[mi*8 + j] + b1[mi*8 + j];
    h = (h > 0.0f) ? h : 0.0f;
    acc += h * w2[mi*8 + j];
  }
  eattr[e] = acc;
}

// ---------------------------------------------------------------------------
// Per-node attention aggregation (srow cached -> sbuf gathered once).
// ---------------------------------------------------------------------------
template<int NE, bool IS_ATOM>
__device__ __forceinline__ float agg_node(
    int n, int lane,
    float* __restrict__ x,
    const float* __restrict__ sbuf, const float* __restrict__ dbuf,
    const float* __restrict__ eattr,
    const int* __restrict__ srcA, const int* __restrict__ srcAV,
    const int* __restrict__ srcVV,
    const float* __restrict__ We, const float* __restrict__ att, int l,
    float* __restrict__ snap)
{
  const float wet  = We[l*HD + lane];
  const float attv = att[l*HD + lane];
  const float dn   = dbuf[n*HD + lane];
  float srow[NE], escore[NE];
#pragma unroll
  for (int e = 0; e < NE; ++e) {
    int src, eidx;
    if (IS_ATOM) {
      if (e < 10) { src = srcA[n*10 + e];       eidx = n*10 + e; }
      else        { src = srcAV[n*15 + (e-10)]; eidx = E_AA + n*15 + (e-10); }
    } else {
      const int nv = n - NA;
      src = srcVV[nv*15 + e]; eidx = E_AA + E_AV + nv*15 + e;
    }
    const float sv = sbuf[src*HD + lane];
    srow[e] = sv;
    float mm = sv + dn + eattr[eidx] * wet;
    mm = (mm >= 0.0f) ? mm : 0.2f * mm;        // leaky_relu(0.2)
    float vv = mm * attv;                       // reduce over d within head
    vv += __shfl_xor(vv, 1); vv += __shfl_xor(vv, 2);
    vv += __shfl_xor(vv, 4); vv += __shfl_xor(vv, 8);
    escore[e] = vv;
  }
  float mx = -INFINITY;
#pragma unroll
  for (int e = 0; e < NE; ++e) mx = fmaxf(mx, escore[e]);
  float den = 0.0f;
#pragma unroll
  for (int e = 0; e < NE; ++e) {
    const float a = expf(escore[e] - mx);
    escore[e] = a; den += a;
  }
  const float inv = 1.0f / den;
  float msg = 0.0f;
#pragma unroll
  for (int e = 0; e < NE; ++e) msg += (escore[e] * inv) * srow[e];
  float xv = x[n*HD + lane] + msg;
  xv = (xv > 0.0f) ? xv : 0.0f;
  x[n*HD + lane] = xv;
  if (!IS_ATOM && snap != nullptr) snap[(n - NA)*HD + lane] = xv;
  return xv;
}

// ---------------------------------------------------------------------------
// Fused layer: agg (atoms+vox in one grid) + LN(l+1) + s/d proj for next layer.
// sbuf ping-pong across launches; dbuf/x rows are node-private (in-place ok).
// ---------------------------------------------------------------------------
__global__ __launch_bounds__(64) void layer_kernel(
    float* __restrict__ x,
    const float* __restrict__ sbuf_in, float* __restrict__ dbuf,
    float* __restrict__ sbuf_out,
    const float* __restrict__ eattr,
    const int* __restrict__ srcA, const int* __restrict__ srcAV,
    const int* __restrict__ srcVV,
    const float* __restrict__ We, const float* __restrict__ att,
    const float* __restrict__ ln_g, const float* __restrict__ ln_b,
    const float* __restrict__ Ws, const float* __restrict__ Wd,
    int l, float* __restrict__ snap, int do_next)
{
  const int n = blockIdx.x, lane = threadIdx.x;
  float xv;
  if (n < NA) {
    if (!do_next) return;   // last layer: atom rows never consumed again
    xv = agg_node<25,true>(n, lane, x, sbuf_in, dbuf, eattr,
                           srcA, srcAV, srcVV, We, att, l, nullptr);
  } else {
    xv = agg_node<15,false>(n, lane, x, sbuf_in, dbuf, eattr,
                            srcA, srcAV, srcVV, We, att, l, snap);
  }
  if (do_next)
    ln_sd(xv, n, lane, l+1, ln_g, ln_b, Ws, Wd, sbuf_out, dbuf);
}

// ---------------------------------------------------------------------------
// Output head (unchanged) + vox_pos passthrough.
// ---------------------------------------------------------------------------
__global__ __launch_bounds__(64) void head_kernel(
    const float* __restrict__ snaps,
    const float* __restrict__ Wo1, const float* __restrict__ bo1,
    const float* __restrict__ Wo2, const float* __restrict__ bo2,
    float* __restrict__ out)
{
  const int n = blockIdx.x;
  const int t = threadIdx.x;
  __shared__ float cat[7*HD];
  __shared__ float o1[HD];
#pragma unroll
  for (int c = 0; c < 7; ++c)
    cat[c*HD + t] = snaps[(size_t)c*NV*HD + n*HD + t];
  __syncthreads();
  float acc = bo1[t];
  for (int j = 0; j < 7*HD; ++j) acc += cat[j] * Wo1[j*HD + t];
  acc = fmaxf(acc, 0.0f);
  o1[t] = acc;
  __syncthreads();
  float acc2 = bo2[t];
#pragma unroll
  for (int j = 0; j < HD; ++j) acc2 += o1[j] * Wo2[j*HD + t];
  out[n*HD + t] = acc2;
}

__global__ __launch_bounds__(256) void copy_pos_kernel(
    const float* __restrict__ vp, float* __restrict__ out)
{
  const int i = blockIdx.x * 256 + threadIdx.x;
  if (i < NV*3) out[ENC_SIZE + i] = vp[i];
}

// ---------------------------------------------------------------------------
extern "C" void kernel_launch(void* const* d_in, const int* in_sizes, int n_in,
                              void* d_out, int out_size, void* d_ws, size_t ws_size,
                              hipStream_t stream)
{
  const float* atom_x    = (const float*)d_in[0];
  const float* atom_pos  = (const float*)d_in[1];
  const float* vox_x     = (const float*)d_in[2];
  const float* vox_pos   = (const float*)d_in[3];
  const float* W_atom_in = (const float*)d_in[4];
  const float* b_atom_in = (const float*)d_in[5];
  const float* W_vox_in  = (const float*)d_in[6];
  const float* b_vox_in  = (const float*)d_in[7];
  const float* emlp_w1   = (const float*)d_in[8];
  const float* emlp_b1   = (const float*)d_in[9];
  const float* emlp_w2   = (const float*)d_in[10];
  const float* emlp_b2   = (const float*)d_in[11];
  const float* ln_g      = (const float*)d_in[12];
  const float* ln_b      = (const float*)d_in[13];
  const float* Ws        = (const float*)d_in[14];
  const float* Wd        = (const float*)d_in[15];
  const float* We        = (const float*)d_in[16];
  const float* att       = (const float*)d_in[17];
  const float* Wo1       = (const float*)d_in[18];
  const float* bo1       = (const float*)d_in[19];
  const float* Wo2       = (const float*)d_in[20];
  const float* bo2       = (const float*)d_in[21];
  float* out = (float*)d_out;

  // workspace layout (floats), ~21.6 MB
  float* ws    = (float*)d_ws;
  float* x     = ws;                          // [NN][HD]
  float* sA    = x  + (size_t)NN*HD;          // [NN][HD] sbuf ping
  float* sB    = sA + (size_t)NN*HD;          // [NN][HD] sbuf pong
  float* dbuf  = sB + (size_t)NN*HD;          // [NN][HD]
  float* eattr = dbuf + (size_t)NN*HD;        // [E_TOT]
  float* snaps = eattr + E_TOT;               // [7][NV][HD]
  int*   srcA  = (int*)(snaps + (size_t)7*NV*HD);
  int*   srcAV = srcA  + E_AA;
  int*   srcVV = srcAV + E_AV;

  // 1. kNN graphs
  knn_kernel<10><<<NA/4, 256, 0, stream>>>(atom_pos, atom_pos, NA, 0,  srcA);
  knn_kernel<15><<<NA/4, 256, 0, stream>>>(atom_pos, vox_pos,  NV, NA, srcAV);
  knn_kernel<15><<<NV/4, 256, 0, stream>>>(vox_pos,  vox_pos,  NV, NA, srcVV);
  // 2. edge attributes
  edge_attr_kernel<<<(E_TOT + 255)/256, 256, 0, stream>>>(
      atom_pos, vox_pos, srcA, srcAV, srcVV,
      emlp_w1, emlp_b1, emlp_w2, emlp_b2, eattr);
  // 3. fused input proj + LN0 + s/d proj
  init_kernel<<<NN, 64, 0, stream>>>(atom_x, vox_x, W_atom_in, b_atom_in,
                                     W_vox_in, b_vox_in, ln_g, ln_b, Ws, Wd,
                                     x, snaps, sA, dbuf);
  // 4. 12 fused GAT layers
  for (int l = 0; l < NLAYER; ++l) {
    float* s_in  = (l & 1) ? sB : sA;
    float* s_out = (l & 1) ? sA : sB;
    float* snap  = (l & 1) ? (snaps + (size_t)(l/2 + 1)*NV*HD) : nullptr;
    layer_kernel<<<NN, 64, 0, stream>>>(x, s_in, dbuf, s_out, eattr,
                                        srcA, srcAV, srcVV, We, att,
                                        ln_g, ln_b, Ws, Wd, l, snap,
                                        (l < NLAYER-1) ? 1 : 0);
  }
  // 5. output head + vox_pos passthrough
  head_kernel<<<NV, 64, 0, stream>>>(snaps, Wo1, bo1, Wo2, bo2, out);
  copy_pos_kernel<<<(NV*3 + 255)/256, 256, 0, stream>>>(vox_pos, out);
}

// Round 3
// 562.461 us; speedup vs baseline: 1.6958x; 1.0452x over previous
//
#include <hip/hip_runtime.h>
#include <math.h>

#define NA 8000
#define NV 4000
#define NN 12000
#define NA_PAD 8192
#define NV_PAD 4096
#define KNN_TILE 1024
#define FEAT 32
#define HD 64
#define NLAYER 12
#define E_AA 80000
#define E_AV 120000
#define E_VV 60000
#define E_TOT 260000
#define ENC_SIZE (NV * HD)
#define EPS 1e-5f

__device__ __forceinline__ float wave_sum64(float v) {
#pragma unroll
  for (int off = 1; off < 64; off <<= 1) v += __shfl_xor(v, off);
  return v;
}

// ---------------------------------------------------------------------------
// Pack candidate positions as [x, y, z, |c|^2] float4, padded to tile multiple
// with cc = +INF (pad candidates never qualify: d2 = qq + INF = INF).
// ---------------------------------------------------------------------------
__global__ __launch_bounds__(256) void pack_kernel(
    const float* __restrict__ apos, const float* __restrict__ vpos,
    float4* __restrict__ apk, float4* __restrict__ vpk)
{
  const int i = blockIdx.x * 256 + threadIdx.x;
  if (i < NA_PAD) {
    float4 r;
    if (i < NA) {
      const float cx = apos[i*3+0], cy = apos[i*3+1], cz = apos[i*3+2];
      r = make_float4(cx, cy, cz, (cx*cx + cy*cy) + cz*cz);
    } else r = make_float4(0.f, 0.f, 0.f, INFINITY);
    apk[i] = r;
  } else {
    const int j = i - NA_PAD;
    if (j < NV_PAD) {
      float4 r;
      if (j < NV) {
        const float cx = vpos[j*3+0], cy = vpos[j*3+1], cz = vpos[j*3+2];
        r = make_float4(cx, cy, cz, (cx*cx + cy*cy) + cz*cz);
      } else r = make_float4(0.f, 0.f, 0.f, INFINITY);
      vpk[j] = r;
    }
  }
}

// ---------------------------------------------------------------------------
// kNN: 8 queries/block (one wave each). Candidates streamed directly from
// global as packed float4 (no LDS); one __syncthreads per 1024-candidate tile
// keeps the 8 waves inside the same 16KB window -> L1 reuse. Wave-global
// sorted top-K list, one entry per lane; inserts behind a scalar ballot
// branch. Lexicographic (d2, idx) tie-break == jax.lax.top_k.
// ---------------------------------------------------------------------------
template<int K, int NC_PAD>
__global__ __launch_bounds__(512) void knn_kernel(
    const float* __restrict__ qpos, const float4* __restrict__ cpk,
    int c_off, int* __restrict__ out_src)
{
  const int tid  = threadIdx.x;
  const int wid  = tid >> 6, lane = tid & 63;
  const int q    = blockIdx.x * 8 + wid;
  const float qx = qpos[q*3+0], qy = qpos[q*3+1], qz = qpos[q*3+2];
  const float qq = (qx*qx + qy*qy) + qz*qz;

  float eD = INFINITY; int eI = 0x7fffffff;   // this lane's entry of the list
  float thrD = INFINITY;                       // K-th best (broadcast)

  for (int t0 = 0; t0 < NC_PAD; t0 += KNN_TILE) {
    __syncthreads();                           // keep waves' streams aligned
#pragma unroll
    for (int it = 0; it < KNN_TILE/64; ++it) {
      const int j = t0 + it*64 + lane;
      const float4 c = cpk[j];
      const float dot = qx*c.x + qy*c.y + qz*c.z;
      const float d2  = (qq - 2.0f*dot) + c.w;
      unsigned long long m = __ballot(d2 < thrD);
      if (m) {
        do {                                   // wave-uniform insert loop
          const int sl = __ffsll(m) - 1;
          m &= (m - 1ULL);
          const float v  = __shfl(d2, sl);
          const int   vi = j - lane + sl;      // t0 + it*64 + sl
          const bool stay = (eD < v) || (eD == v && eI < vi);
          const float pD = __shfl_up(eD, 1);
          const int   pI = __shfl_up(eI, 1);
          int pS = __shfl_up(stay ? 1 : 0, 1);
          if (lane == 0) pS = 1;
          eD = stay ? eD : (pS ? v  : pD);
          eI = stay ? eI : (pS ? vi : pI);
        } while (m);
        thrD = __shfl(eD, K-1);
      }
    }
  }
  if (lane < K) out_src[q*K + lane] = eI + c_off;
}

// ---------------------------------------------------------------------------
// LayerNorm + s/d projection for one node row held across the wave's lanes.
// ---------------------------------------------------------------------------
__device__ __forceinline__ void ln_sd(
    float v, int node, int lane, int l,
    const float* __restrict__ ln_g, const float* __restrict__ ln_b,
    const float* __restrict__ Ws, const float* __restrict__ Wd,
    float* __restrict__ sbuf, float* __restrict__ dbuf)
{
  const float m = wave_sum64(v) * (1.0f/64.0f);
  const float c = v - m;
  const float var = wave_sum64(c*c) * (1.0f/64.0f);
  const float hn = c * rsqrtf(var + EPS) * ln_g[l*HD + lane] + ln_b[l*HD + lane];
  const float* ws = Ws + l*HD*HD;
  const float* wd = Wd + l*HD*HD;
  float accs = 0.0f, accd = 0.0f;
#pragma unroll
  for (int j = 0; j < HD; ++j) {
    const float hj = __shfl(hn, j);
    accs += hj * ws[j*HD + lane];
    accd += hj * wd[j*HD + lane];
  }
  sbuf[node*HD + lane] = accs;
  dbuf[node*HD + lane] = accd;
}

// ---------------------------------------------------------------------------
// Fused first kernel: input projection + snapshot0 + LN(0) + s/d projection.
// ---------------------------------------------------------------------------
__global__ __launch_bounds__(64) void init_kernel(
    const float* __restrict__ atom_x, const float* __restrict__ vox_x,
    const float* __restrict__ Wa, const float* __restrict__ ba,
    const float* __restrict__ Wv, const float* __restrict__ bv,
    const float* __restrict__ ln_g, const float* __restrict__ ln_b,
    const float* __restrict__ Ws, const float* __restrict__ Wd,
    float* __restrict__ x, float* __restrict__ snap0,
    float* __restrict__ sbuf, float* __restrict__ dbuf)
{
  const int node = blockIdx.x;
  const int t    = threadIdx.x;
  const float* in; const float* W; const float* b;
  if (node < NA) { in = atom_x + node*FEAT;     W = Wa; b = ba; }
  else           { in = vox_x + (node-NA)*FEAT; W = Wv; b = bv; }
  float acc = b[t];
#pragma unroll
  for (int j = 0; j < FEAT; ++j) acc += in[j] * W[j*HD + t];
  x[node*HD + t] = acc;
  if (node >= NA) snap0[(node-NA)*HD + t] = acc;
  ln_sd(acc, node, t, 0, ln_g, ln_b, Ws, Wd, sbuf, dbuf);
}

// ---------------------------------------------------------------------------
// Edge attribute MLP.
// ---------------------------------------------------------------------------
__device__ __forceinline__ void load_pos(const float* ap, const float* vp,
                                         int i, float& px, float& py, float& pz)
{
  const float* p = (i < NA) ? (ap + i*3) : (vp + (i - NA)*3);
  px = p[0]; py = p[1]; pz = p[2];
}

__global__ __launch_bounds__(256) void edge_attr_kernel(
    const float* __restrict__ atom_pos, const float* __restrict__ vox_pos,
    const int* __restrict__ srcA, const int* __restrict__ srcAV,
    const int* __restrict__ srcVV,
    const float* __restrict__ w1, const float* __restrict__ b1,
    const float* __restrict__ w2, const float* __restrict__ b2,
    float* __restrict__ eattr)
{
  const int e = blockIdx.x * 256 + threadIdx.x;
  if (e >= E_TOT) return;
  int s, d, mi;
  if (e < E_AA)              { mi = 0; s = srcA[e];                 d = e / 10; }
  else if (e < E_AA + E_AV)  { mi = 1; const int t = e - E_AA;      s = srcAV[t]; d = t / 15; }
  else                       { mi = 2; const int t = e - E_AA - E_AV; s = srcVV[t]; d = NA + t / 15; }
  float sx, sy, sz, dx_, dy_, dz_;
  load_pos(atom_pos, vox_pos, s, sx, sy, sz);
  load_pos(atom_pos, vox_pos, d, dx_, dy_, dz_);
  const float ex = sx - dx_, ey = sy - dy_, ez = sz - dz_;
  const float dist = sqrtf(ex*ex + ey*ey + ez*ez);
  float acc = b2[mi];
#pragma unroll
  for (int j = 0; j < 8; ++j) {
    float h = dist * w1[mi*8 + j] + b1[mi*8 + j];
    h = (h > 0.0f) ? h : 0.0f;
    acc += h * w2[mi*8 + j];
  }
  eattr[e] = acc;
}

// ---------------------------------------------------------------------------
// Per-node attention aggregation (srow cached -> sbuf gathered once).
// ---------------------------------------------------------------------------
template<int NE, bool IS_ATOM>
__device__ __forceinline__ float agg_node(
    int n, int lane,
    float* __restrict__ x,
    const float* __restrict__ sbuf, const float* __restrict__ dbuf,
    const float* __restrict__ eattr,
    const int* __restrict__ srcA, const int* __restrict__ srcAV,
    const int* __restrict__ srcVV,
    const float* __restrict__ We, const float* __restrict__ att, int l,
    float* __restrict__ snap)
{
  const float wet  = We[l*HD + lane];
  const float attv = att[l*HD + lane];
  const float dn   = dbuf[n*HD + lane];
  float srow[NE], escore[NE];
#pragma unroll
  for (int e = 0; e < NE; ++e) {
    int src, eidx;
    if (IS_ATOM) {
      if (e < 10) { src = srcA[n*10 + e];       eidx = n*10 + e; }
      else        { src = srcAV[n*15 + (e-10)]; eidx = E_AA + n*15 + (e-10); }
    } else {
      const int nv = n - NA;
      src = srcVV[nv*15 + e]; eidx = E_AA + E_AV + nv*15 + e;
    }
    const float sv = sbuf[src*HD + lane];
    srow[e] = sv;
    float mm = sv + dn + eattr[eidx] * wet;
    mm = (mm >= 0.0f) ? mm : 0.2f * mm;        // leaky_relu(0.2)
    float vv = mm * attv;                       // reduce over d within head
    vv += __shfl_xor(vv, 1); vv += __shfl_xor(vv, 2);
    vv += __shfl_xor(vv, 4); vv += __shfl_xor(vv, 8);
    escore[e] = vv;
  }
  float mx = -INFINITY;
#pragma unroll
  for (int e = 0; e < NE; ++e) mx = fmaxf(mx, escore[e]);
  float den = 0.0f;
#pragma unroll
  for (int e = 0; e < NE; ++e) {
    const float a = expf(escore[e] - mx);
    escore[e] = a; den += a;
  }
  const float inv = 1.0f / den;
  float msg = 0.0f;
#pragma unroll
  for (int e = 0; e < NE; ++e) msg += (escore[e] * inv) * srow[e];
  float xv = x[n*HD + lane] + msg;
  xv = (xv > 0.0f) ? xv : 0.0f;
  x[n*HD + lane] = xv;
  if (!IS_ATOM && snap != nullptr) snap[(n - NA)*HD + lane] = xv;
  return xv;
}

// ---------------------------------------------------------------------------
// Fused layer: agg (atoms+vox) + LN(l+1) + s/d proj for next layer.
// ---------------------------------------------------------------------------
__global__ __launch_bounds__(64) void layer_kernel(
    float* __restrict__ x,
    const float* __restrict__ sbuf_in, float* __restrict__ dbuf,
    float* __restrict__ sbuf_out,
    const float* __restrict__ eattr,
    const int* __restrict__ srcA, const int* __restrict__ srcAV,
    const int* __restrict__ srcVV,
    const float* __restrict__ We, const float* __restrict__ att,
    const float* __restrict__ ln_g, const float* __restrict__ ln_b,
    const float* __restrict__ Ws, const float* __restrict__ Wd,
    int l, float* __restrict__ snap, int do_next)
{
  const int n = blockIdx.x, lane = threadIdx.x;
  float xv;
  if (n < NA) {
    if (!do_next) return;   // last layer: atom rows never consumed again
    xv = agg_node<25,true>(n, lane, x, sbuf_in, dbuf, eattr,
                           srcA, srcAV, srcVV, We, att, l, nullptr);
  } else {
    xv = agg_node<15,false>(n, lane, x, sbuf_in, dbuf, eattr,
                            srcA, srcAV, srcVV, We, att, l, snap);
  }
  if (do_next)
    ln_sd(xv, n, lane, l+1, ln_g, ln_b, Ws, Wd, sbuf_out, dbuf);
}

// ---------------------------------------------------------------------------
// Output head + vox_pos passthrough.
// ---------------------------------------------------------------------------
__global__ __launch_bounds__(64) void head_kernel(
    const float* __restrict__ snaps,
    const float* __restrict__ Wo1, const float* __restrict__ bo1,
    const float* __restrict__ Wo2, const float* __restrict__ bo2,
    float* __restrict__ out)
{
  const int n = blockIdx.x;
  const int t = threadIdx.x;
  __shared__ float cat[7*HD];
  __shared__ float o1[HD];
#pragma unroll
  for (int c = 0; c < 7; ++c)
    cat[c*HD + t] = snaps[(size_t)c*NV*HD + n*HD + t];
  __syncthreads();
  float acc = bo1[t];
  for (int j = 0; j < 7*HD; ++j) acc += cat[j] * Wo1[j*HD + t];
  acc = fmaxf(acc, 0.0f);
  o1[t] = acc;
  __syncthreads();
  float acc2 = bo2[t];
#pragma unroll
  for (int j = 0; j < HD; ++j) acc2 += o1[j] * Wo2[j*HD + t];
  out[n*HD + t] = acc2;
}

__global__ __launch_bounds__(256) void copy_pos_kernel(
    const float* __restrict__ vp, float* __restrict__ out)
{
  const int i = blockIdx.x * 256 + threadIdx.x;
  if (i < NV*3) out[ENC_SIZE + i] = vp[i];
}

// ---------------------------------------------------------------------------
extern "C" void kernel_launch(void* const* d_in, const int* in_sizes, int n_in,
                              void* d_out, int out_size, void* d_ws, size_t ws_size,
                              hipStream_t stream)
{
  const float* atom_x    = (const float*)d_in[0];
  const float* atom_pos  = (const float*)d_in[1];
  const float* vox_x     = (const float*)d_in[2];
  const float* vox_pos   = (const float*)d_in[3];
  const float* W_atom_in = (const float*)d_in[4];
  const float* b_atom_in = (const float*)d_in[5];
  const float* W_vox_in  = (const float*)d_in[6];
  const float* b_vox_in  = (const float*)d_in[7];
  const float* emlp_w1   = (const float*)d_in[8];
  const float* emlp_b1   = (const float*)d_in[9];
  const float* emlp_w2   = (const float*)d_in[10];
  const float* emlp_b2   = (const float*)d_in[11];
  const float* ln_g      = (const float*)d_in[12];
  const float* ln_b      = (const float*)d_in[13];
  const float* Ws        = (const float*)d_in[14];
  const float* Wd        = (const float*)d_in[15];
  const float* We        = (const float*)d_in[16];
  const float* att       = (const float*)d_in[17];
  const float* Wo1       = (const float*)d_in[18];
  const float* bo1       = (const float*)d_in[19];
  const float* Wo2       = (const float*)d_in[20];
  const float* bo2       = (const float*)d_in[21];
  float* out = (float*)d_out;

  // workspace layout (floats), ~21.8 MB
  float* ws    = (float*)d_ws;
  float* x     = ws;                          // [NN][HD]
  float* sA    = x  + (size_t)NN*HD;          // [NN][HD] sbuf ping
  float* sB    = sA + (size_t)NN*HD;          // [NN][HD] sbuf pong
  float* dbuf  = sB + (size_t)NN*HD;          // [NN][HD]
  float* eattr = dbuf + (size_t)NN*HD;        // [E_TOT]
  float* snaps = eattr + E_TOT;               // [7][NV][HD]
  int*   srcA  = (int*)(snaps + (size_t)7*NV*HD);
  int*   srcAV = srcA  + E_AA;
  int*   srcVV = srcAV + E_AV;
  float4* apk  = (float4*)(srcVV + E_VV);     // [NA_PAD] packed atoms
  float4* vpk  = apk + NA_PAD;                // [NV_PAD] packed voxels

  // 1. pack candidates, then kNN graphs
  pack_kernel<<<(NA_PAD + NV_PAD + 255)/256, 256, 0, stream>>>(
      atom_pos, vox_pos, apk, vpk);
  knn_kernel<10, NA_PAD><<<NA/8, 512, 0, stream>>>(atom_pos, apk, 0,  srcA);
  knn_kernel<15, NV_PAD><<<NA/8, 512, 0, stream>>>(atom_pos, vpk, NA, srcAV);
  knn_kernel<15, NV_PAD><<<NV/8, 512, 0, stream>>>(vox_pos,  vpk, NA, srcVV);
  // 2. edge attributes
  edge_attr_kernel<<<(E_TOT + 255)/256, 256, 0, stream>>>(
      atom_pos, vox_pos, srcA, srcAV, srcVV,
      emlp_w1, emlp_b1, emlp_w2, emlp_b2, eattr);
  // 3. fused input proj + LN0 + s/d proj
  init_kernel<<<NN, 64, 0, stream>>>(atom_x, vox_x, W_atom_in, b_atom_in,
                                     W_vox_in, b_vox_in, ln_g, ln_b, Ws, Wd,
                                     x, snaps, sA, dbuf);
  // 4. 12 fused GAT layers
  for (int l = 0; l < NLAYER; ++l) {
    float* s_in  = (l & 1) ? sB : sA;
    float* s_out = (l & 1) ? sA : sB;
    float* snap  = (l & 1) ? (snaps + (size_t)(l/2 + 1)*NV*HD) : nullptr;
    layer_kernel<<<NN, 64, 0, stream>>>(x, s_in, dbuf, s_out, eattr,
                                        srcA, srcAV, srcVV, We, att,
                                        ln_g, ln_b, Ws, Wd, l, snap,
                                        (l < NLAYER-1) ? 1 : 0);
  }
  // 5. output head + vox_pos passthrough
  head_kernel<<<NV, 64, 0, stream>>>(snaps, Wo1, bo1, Wo2, bo2, out);
  copy_pos_kernel<<<(NV*3 + 255)/256, 256, 0, stream>>>(vox_pos, out);
}

// Round 5
// 489.902 us; speedup vs baseline: 1.9470x; 1.1481x over previous
//
#include <hip/hip_runtime.h>
#include <math.h>

#define NA 8000
#define NV 4000
#define NN 12000
#define NA_PAD 8192
#define NV_PAD 4096
#define KNN_TILE 1024
#define FEAT 32
#define HD 64
#define NLAYER 12
#define E_AA 80000
#define E_AV 120000
#define E_VV 60000
#define E_TOT 260000
#define ENC_SIZE (NV * HD)
#define EPS 1e-5f

__device__ __forceinline__ float wave_sum64(float v) {
#pragma unroll
  for (int off = 1; off < 64; off <<= 1) v += __shfl_xor(v, off);
  return v;
}

// ---------------------------------------------------------------------------
// Pack candidate positions as [x, y, z, |c|^2] float4, padded with cc=+INF.
// ---------------------------------------------------------------------------
__global__ __launch_bounds__(256) void pack_kernel(
    const float* __restrict__ apos, const float* __restrict__ vpos,
    float4* __restrict__ apk, float4* __restrict__ vpk)
{
  const int i = blockIdx.x * 256 + threadIdx.x;
  if (i < NA_PAD) {
    float4 r;
    if (i < NA) {
      const float cx = apos[i*3+0], cy = apos[i*3+1], cz = apos[i*3+2];
      r = make_float4(cx, cy, cz, (cx*cx + cy*cy) + cz*cz);
    } else r = make_float4(0.f, 0.f, 0.f, INFINITY);
    apk[i] = r;
  } else {
    const int j = i - NA_PAD;
    if (j < NV_PAD) {
      float4 r;
      if (j < NV) {
        const float cx = vpos[j*3+0], cy = vpos[j*3+1], cz = vpos[j*3+2];
        r = make_float4(cx, cy, cz, (cx*cx + cy*cy) + cz*cz);
      } else r = make_float4(0.f, 0.f, 0.f, INFINITY);
      vpk[j] = r;
    }
  }
}

// ---------------------------------------------------------------------------
// kNN: 8 queries/block (one wave each). Candidates streamed directly from
// global as packed float4 (no LDS); one __syncthreads per 1024-candidate tile
// keeps the 8 waves inside the same 16KB window -> L1 reuse. Wave-global
// sorted top-K list, one entry per lane; inserts behind a scalar ballot
// branch. Lexicographic (d2, idx) tie-break == jax.lax.top_k.
// (Reverted VERBATIM to the round-3 passing version: the flattened/prefetch
// rewrite changed FMA contraction of d2 by ulps and flipped near-tie
// neighbor selections vs the exact reference.)
// ---------------------------------------------------------------------------
template<int K, int NC_PAD>
__global__ __launch_bounds__(512) void knn_kernel(
    const float* __restrict__ qpos, const float4* __restrict__ cpk,
    int c_off, int* __restrict__ out_src)
{
  const int tid  = threadIdx.x;
  const int wid  = tid >> 6, lane = tid & 63;
  const int q    = blockIdx.x * 8 + wid;
  const float qx = qpos[q*3+0], qy = qpos[q*3+1], qz = qpos[q*3+2];
  const float qq = (qx*qx + qy*qy) + qz*qz;

  float eD = INFINITY; int eI = 0x7fffffff;   // this lane's entry of the list
  float thrD = INFINITY;                       // K-th best (broadcast)

  for (int t0 = 0; t0 < NC_PAD; t0 += KNN_TILE) {
    __syncthreads();                           // keep waves' streams aligned
#pragma unroll
    for (int it = 0; it < KNN_TILE/64; ++it) {
      const int j = t0 + it*64 + lane;
      const float4 c = cpk[j];
      const float dot = qx*c.x + qy*c.y + qz*c.z;
      const float d2  = (qq - 2.0f*dot) + c.w;
      unsigned long long m = __ballot(d2 < thrD);
      if (m) {
        do {                                   // wave-uniform insert loop
          const int sl = __ffsll(m) - 1;
          m &= (m - 1ULL);
          const float v  = __shfl(d2, sl);
          const int   vi = j - lane + sl;      // t0 + it*64 + sl
          const bool stay = (eD < v) || (eD == v && eI < vi);
          const float pD = __shfl_up(eD, 1);
          const int   pI = __shfl_up(eI, 1);
          int pS = __shfl_up(stay ? 1 : 0, 1);
          if (lane == 0) pS = 1;
          eD = stay ? eD : (pS ? v  : pD);
          eI = stay ? eI : (pS ? vi : pI);
        } while (m);
        thrD = __shfl(eD, K-1);
      }
    }
  }
  if (lane < K) out_src[q*K + lane] = eI + c_off;
}

// ---------------------------------------------------------------------------
// LayerNorm + s/d projection, single-wave version (used by init only).
// ---------------------------------------------------------------------------
__device__ __forceinline__ void ln_sd(
    float v, int node, int lane, int l,
    const float* __restrict__ ln_g, const float* __restrict__ ln_b,
    const float* __restrict__ Ws, const float* __restrict__ Wd,
    float* __restrict__ sbuf, float* __restrict__ dbuf)
{
  const float m = wave_sum64(v) * (1.0f/64.0f);
  const float c = v - m;
  const float var = wave_sum64(c*c) * (1.0f/64.0f);
  const float hn = c * rsqrtf(var + EPS) * ln_g[l*HD + lane] + ln_b[l*HD + lane];
  const float* ws = Ws + (size_t)l*HD*HD;
  const float* wd = Wd + (size_t)l*HD*HD;
  float accs = 0.0f, accd = 0.0f;
#pragma unroll
  for (int j = 0; j < HD; ++j) {
    const float hj = __shfl(hn, j);
    accs += hj * ws[j*HD + lane];
    accd += hj * wd[j*HD + lane];
  }
  sbuf[node*HD + lane] = accs;
  dbuf[node*HD + lane] = accd;
}

// ---------------------------------------------------------------------------
// Fused first kernel: input projection + snapshot0 + LN(0) + s/d projection.
// ---------------------------------------------------------------------------
__global__ __launch_bounds__(64) void init_kernel(
    const float* __restrict__ atom_x, const float* __restrict__ vox_x,
    const float* __restrict__ Wa, const float* __restrict__ ba,
    const float* __restrict__ Wv, const float* __restrict__ bv,
    const float* __restrict__ ln_g, const float* __restrict__ ln_b,
    const float* __restrict__ Ws, const float* __restrict__ Wd,
    float* __restrict__ x, float* __restrict__ snap0,
    float* __restrict__ sbuf, float* __restrict__ dbuf)
{
  const int node = blockIdx.x;
  const int t    = threadIdx.x;
  const float* in; const float* W; const float* b;
  if (node < NA) { in = atom_x + node*FEAT;     W = Wa; b = ba; }
  else           { in = vox_x + (node-NA)*FEAT; W = Wv; b = bv; }
  float acc = b[t];
#pragma unroll
  for (int j = 0; j < FEAT; ++j) acc += in[j] * W[j*HD + t];
  x[node*HD + t] = acc;
  if (node >= NA) snap0[(node-NA)*HD + t] = acc;
  ln_sd(acc, node, t, 0, ln_g, ln_b, Ws, Wd, sbuf, dbuf);
}

// ---------------------------------------------------------------------------
// Edge attribute MLP.
// ---------------------------------------------------------------------------
__device__ __forceinline__ void load_pos(const float* ap, const float* vp,
                                         int i, float& px, float& py, float& pz)
{
  const float* p = (i < NA) ? (ap + i*3) : (vp + (i - NA)*3);
  px = p[0]; py = p[1]; pz = p[2];
}

__global__ __launch_bounds__(256) void edge_attr_kernel(
    const float* __restrict__ atom_pos, const float* __restrict__ vox_pos,
    const int* __restrict__ srcA, const int* __restrict__ srcAV,
    const int* __restrict__ srcVV,
    const float* __restrict__ w1, const float* __restrict__ b1,
    const float* __restrict__ w2, const float* __restrict__ b2,
    float* __restrict__ eattr)
{
  const int e = blockIdx.x * 256 + threadIdx.x;
  if (e >= E_TOT) return;
  int s, d, mi;
  if (e < E_AA)              { mi = 0; s = srcA[e];                 d = e / 10; }
  else if (e < E_AA + E_AV)  { mi = 1; const int t = e - E_AA;      s = srcAV[t]; d = t / 15; }
  else                       { mi = 2; const int t = e - E_AA - E_AV; s = srcVV[t]; d = NA + t / 15; }
  float sx, sy, sz, dx_, dy_, dz_;
  load_pos(atom_pos, vox_pos, s, sx, sy, sz);
  load_pos(atom_pos, vox_pos, d, dx_, dy_, dz_);
  const float ex = sx - dx_, ey = sy - dy_, ez = sz - dz_;
  const float dist = sqrtf(ex*ex + ey*ey + ez*ez);
  float acc = b2[mi];
#pragma unroll
  for (int j = 0; j < 8; ++j) {
    float h = dist * w1[mi*8 + j] + b1[mi*8 + j];
    h = (h > 0.0f) ? h : 0.0f;
    acc += h * w2[mi*8 + j];
  }
  eattr[e] = acc;
}

// ---------------------------------------------------------------------------
// Per-node attention aggregation (one wave per node).
// ---------------------------------------------------------------------------
template<int NE, bool IS_ATOM>
__device__ __forceinline__ float agg_node(
    int n, int lane,
    float* __restrict__ x,
    const float* __restrict__ sbuf, const float* __restrict__ dbuf,
    const float* __restrict__ eattr,
    const int* __restrict__ srcA, const int* __restrict__ srcAV,
    const int* __restrict__ srcVV,
    const float* __restrict__ We, const float* __restrict__ att, int l,
    float* __restrict__ snap)
{
  const float wet  = We[l*HD + lane];
  const float attv = att[l*HD + lane];
  const float dn   = dbuf[n*HD + lane];
  float srow[NE], escore[NE];
#pragma unroll
  for (int e = 0; e < NE; ++e) {
    int src, eidx;
    if (IS_ATOM) {
      if (e < 10) { src = srcA[n*10 + e];       eidx = n*10 + e; }
      else        { src = srcAV[n*15 + (e-10)]; eidx = E_AA + n*15 + (e-10); }
    } else {
      const int nv = n - NA;
      src = srcVV[nv*15 + e]; eidx = E_AA + E_AV + nv*15 + e;
    }
    const float sv = sbuf[src*HD + lane];
    srow[e] = sv;
    float mm = sv + dn + eattr[eidx] * wet;
    mm = (mm >= 0.0f) ? mm : 0.2f * mm;        // leaky_relu(0.2)
    float vv = mm * attv;                       // reduce over d within head
    vv += __shfl_xor(vv, 1); vv += __shfl_xor(vv, 2);
    vv += __shfl_xor(vv, 4); vv += __shfl_xor(vv, 8);
    escore[e] = vv;
  }
  float mx = -INFINITY;
#pragma unroll
  for (int e = 0; e < NE; ++e) mx = fmaxf(mx, escore[e]);
  float den = 0.0f;
#pragma unroll
  for (int e = 0; e < NE; ++e) {
    const float a = expf(escore[e] - mx);
    escore[e] = a; den += a;
  }
  const float inv = 1.0f / den;
  float msg = 0.0f;
#pragma unroll
  for (int e = 0; e < NE; ++e) msg += (escore[e] * inv) * srow[e];
  float xv = x[n*HD + lane] + msg;
  xv = (xv > 0.0f) ? xv : 0.0f;
  x[n*HD + lane] = xv;
  if (!IS_ATOM && snap != nullptr) snap[(n - NA)*HD + lane] = xv;
  return xv;
}

// ---------------------------------------------------------------------------
// Fused layer: 4 nodes/block (one wave each) agg, then LN(l+1) + s/d proj
// with the j-loop sliced across the block's 4 waves so each weight load
// serves 4 nodes (4x less weight traffic). LDS partial reduction, fixed order.
// ---------------------------------------------------------------------------
__global__ __launch_bounds__(256) void layer_kernel(
    float* __restrict__ x,
    const float* __restrict__ sbuf_in, float* __restrict__ dbuf,
    float* __restrict__ sbuf_out,
    const float* __restrict__ eattr,
    const int* __restrict__ srcA, const int* __restrict__ srcAV,
    const int* __restrict__ srcVV,
    const float* __restrict__ We, const float* __restrict__ att,
    const float* __restrict__ ln_g, const float* __restrict__ ln_b,
    const float* __restrict__ Ws, const float* __restrict__ Wd,
    int l, float* __restrict__ snap, int do_next)
{
  const int wid = threadIdx.x >> 6, lane = threadIdx.x & 63;
  const int n = blockIdx.x * 4 + wid;       // blocks are node-type homogeneous
  __shared__ float hn_sh[4][HD];
  __shared__ float part[4][4][2][HD];

  float xv;
  if (n < NA) {
    if (!do_next) return;                    // whole block returns uniformly
    xv = agg_node<25,true>(n, lane, x, sbuf_in, dbuf, eattr,
                           srcA, srcAV, srcVV, We, att, l, nullptr);
  } else {
    xv = agg_node<15,false>(n, lane, x, sbuf_in, dbuf, eattr,
                            srcA, srcAV, srcVV, We, att, l, snap);
  }
  if (!do_next) return;

  // LayerNorm for layer l+1 (per-wave, same arithmetic as before)
  const int ln = l + 1;
  const float mean = wave_sum64(xv) * (1.0f/64.0f);
  const float cc   = xv - mean;
  const float var  = wave_sum64(cc*cc) * (1.0f/64.0f);
  const float hn   = cc * rsqrtf(var + EPS) * ln_g[ln*HD + lane] + ln_b[ln*HD + lane];
  hn_sh[wid][lane] = hn;
  __syncthreads();

  // j-sliced projection: wave wid covers j in [wid*16, wid*16+16) for 4 nodes
  const float* wsp = Ws + (size_t)ln*HD*HD;
  const float* wdp = Wd + (size_t)ln*HD*HD;
  float as0=0.f, as1=0.f, as2=0.f, as3=0.f;
  float ad0=0.f, ad1=0.f, ad2=0.f, ad3=0.f;
#pragma unroll
  for (int jj = 0; jj < 16; ++jj) {
    const int j = wid*16 + jj;
    const float wvs = wsp[j*HD + lane];
    const float wvd = wdp[j*HD + lane];
    const float h0 = hn_sh[0][j], h1 = hn_sh[1][j];
    const float h2 = hn_sh[2][j], h3 = hn_sh[3][j];
    as0 += h0*wvs; ad0 += h0*wvd;
    as1 += h1*wvs; ad1 += h1*wvd;
    as2 += h2*wvs; ad2 += h2*wvd;
    as3 += h3*wvs; ad3 += h3*wvd;
  }
  part[wid][0][0][lane] = as0; part[wid][0][1][lane] = ad0;
  part[wid][1][0][lane] = as1; part[wid][1][1][lane] = ad1;
  part[wid][2][0][lane] = as2; part[wid][2][1][lane] = ad2;
  part[wid][3][0][lane] = as3; part[wid][3][1][lane] = ad3;
  __syncthreads();

  const float accs = ((part[0][wid][0][lane] + part[1][wid][0][lane])
                    + (part[2][wid][0][lane] + part[3][wid][0][lane]));
  const float accd = ((part[0][wid][1][lane] + part[1][wid][1][lane])
                    + (part[2][wid][1][lane] + part[3][wid][1][lane]));
  sbuf_out[n*HD + lane] = accs;
  dbuf[n*HD + lane]     = accd;
}

// ---------------------------------------------------------------------------
// Output head: 4 vox nodes/block, j-sliced matmuls amortize weight loads 4x.
// ---------------------------------------------------------------------------
__global__ __launch_bounds__(256) void head_kernel(
    const float* __restrict__ snaps,
    const float* __restrict__ Wo1, const float* __restrict__ bo1,
    const float* __restrict__ Wo2, const float* __restrict__ bo2,
    float* __restrict__ out)
{
  const int wid = threadIdx.x >> 6, lane = threadIdx.x & 63;
  const int n = blockIdx.x * 4 + wid;
  __shared__ float cat[4][7*HD];
  __shared__ float part[4][4][HD];
  __shared__ float o1[4][HD];

#pragma unroll
  for (int c = 0; c < 7; ++c)
    cat[wid][c*HD + lane] = snaps[(size_t)c*NV*HD + n*HD + lane];
  __syncthreads();

  float a0=0.f, a1=0.f, a2=0.f, a3=0.f;
  for (int jj = 0; jj < 112; ++jj) {
    const int j = wid*112 + jj;
    const float w = Wo1[j*HD + lane];
    a0 += cat[0][j]*w; a1 += cat[1][j]*w;
    a2 += cat[2][j]*w; a3 += cat[3][j]*w;
  }
  part[wid][0][lane] = a0; part[wid][1][lane] = a1;
  part[wid][2][lane] = a2; part[wid][3][lane] = a3;
  __syncthreads();

  float acc = bo1[lane] + ((part[0][wid][lane] + part[1][wid][lane])
                         + (part[2][wid][lane] + part[3][wid][lane]));
  acc = fmaxf(acc, 0.0f);
  o1[wid][lane] = acc;
  __syncthreads();

  float b0=0.f, b1=0.f, b2=0.f, b3=0.f;
#pragma unroll
  for (int jj = 0; jj < 16; ++jj) {
    const int j = wid*16 + jj;
    const float w = Wo2[j*HD + lane];
    b0 += o1[0][j]*w; b1 += o1[1][j]*w;
    b2 += o1[2][j]*w; b3 += o1[3][j]*w;
  }
  __syncthreads();                       // part reuse
  part[wid][0][lane] = b0; part[wid][1][lane] = b1;
  part[wid][2][lane] = b2; part[wid][3][lane] = b3;
  __syncthreads();

  const float acc2 = bo2[lane] + ((part[0][wid][lane] + part[1][wid][lane])
                                + (part[2][wid][lane] + part[3][wid][lane]));
  out[n*HD + lane] = acc2;
}

__global__ __launch_bounds__(256) void copy_pos_kernel(
    const float* __restrict__ vp, float* __restrict__ out)
{
  const int i = blockIdx.x * 256 + threadIdx.x;
  if (i < NV*3) out[ENC_SIZE + i] = vp[i];
}

// ---------------------------------------------------------------------------
extern "C" void kernel_launch(void* const* d_in, const int* in_sizes, int n_in,
                              void* d_out, int out_size, void* d_ws, size_t ws_size,
                              hipStream_t stream)
{
  const float* atom_x    = (const float*)d_in[0];
  const float* atom_pos  = (const float*)d_in[1];
  const float* vox_x     = (const float*)d_in[2];
  const float* vox_pos   = (const float*)d_in[3];
  const float* W_atom_in = (const float*)d_in[4];
  const float* b_atom_in = (const float*)d_in[5];
  const float* W_vox_in  = (const float*)d_in[6];
  const float* b_vox_in  = (const float*)d_in[7];
  const float* emlp_w1   = (const float*)d_in[8];
  const float* emlp_b1   = (const float*)d_in[9];
  const float* emlp_w2   = (const float*)d_in[10];
  const float* emlp_b2   = (const float*)d_in[11];
  const float* ln_g      = (const float*)d_in[12];
  const float* ln_b      = (const float*)d_in[13];
  const float* Ws        = (const float*)d_in[14];
  const float* Wd        = (const float*)d_in[15];
  const float* We        = (const float*)d_in[16];
  const float* att       = (const float*)d_in[17];
  const float* Wo1       = (const float*)d_in[18];
  const float* bo1       = (const float*)d_in[19];
  const float* Wo2       = (const float*)d_in[20];
  const float* bo2       = (const float*)d_in[21];
  float* out = (float*)d_out;

  // workspace layout (floats), ~21.8 MB
  float* ws    = (float*)d_ws;
  float* x     = ws;                          // [NN][HD]
  float* sA    = x  + (size_t)NN*HD;          // [NN][HD] sbuf ping
  float* sB    = sA + (size_t)NN*HD;          // [NN][HD] sbuf pong
  float* dbuf  = sB + (size_t)NN*HD;          // [NN][HD]
  float* eattr = dbuf + (size_t)NN*HD;        // [E_TOT]
  float* snaps = eattr + E_TOT;               // [7][NV][HD]
  int*   srcA  = (int*)(snaps + (size_t)7*NV*HD);
  int*   srcAV = srcA  + E_AA;
  int*   srcVV = srcAV + E_AV;
  float4* apk  = (float4*)(srcVV + E_VV);     // [NA_PAD] packed atoms
  float4* vpk  = apk + NA_PAD;                // [NV_PAD] packed voxels

  // 1. pack candidates, then kNN graphs
  pack_kernel<<<(NA_PAD + NV_PAD + 255)/256, 256, 0, stream>>>(
      atom_pos, vox_pos, apk, vpk);
  knn_kernel<10, NA_PAD><<<NA/8, 512, 0, stream>>>(atom_pos, apk, 0,  srcA);
  knn_kernel<15, NV_PAD><<<NA/8, 512, 0, stream>>>(atom_pos, vpk, NA, srcAV);
  knn_kernel<15, NV_PAD><<<NV/8, 512, 0, stream>>>(vox_pos,  vpk, NA, srcVV);
  // 2. edge attributes
  edge_attr_kernel<<<(E_TOT + 255)/256, 256, 0, stream>>>(
      atom_pos, vox_pos, srcA, srcAV, srcVV,
      emlp_w1, emlp_b1, emlp_w2, emlp_b2, eattr);
  // 3. fused input proj + LN0 + s/d proj
  init_kernel<<<NN, 64, 0, stream>>>(atom_x, vox_x, W_atom_in, b_atom_in,
                                     W_vox_in, b_vox_in, ln_g, ln_b, Ws, Wd,
                                     x, snaps, sA, dbuf);
  // 4. 12 fused GAT layers (4 nodes/block; blocks are type-homogeneous)
  for (int l = 0; l < NLAYER; ++l) {
    float* s_in  = (l & 1) ? sB : sA;
    float* s_out = (l & 1) ? sA : sB;
    float* snap  = (l & 1) ? (snaps + (size_t)(l/2 + 1)*NV*HD) : nullptr;
    layer_kernel<<<NN/4, 256, 0, stream>>>(x, s_in, dbuf, s_out, eattr,
                                           srcA, srcAV, srcVV, We, att,
                                           ln_g, ln_b, Ws, Wd, l, snap,
                                           (l < NLAYER-1) ? 1 : 0);
  }
  // 5. output head + vox_pos passthrough
  head_kernel<<<NV/4, 256, 0, stream>>>(snaps, Wo1, bo1, Wo2, bo2, out);
  copy_pos_kernel<<<(NV*3 + 255)/256, 256, 0, stream>>>(vox_pos, out);
}